// Round 20
// baseline (228.626 us; speedup 1.0000x reference)
//
#include <hip/hip_runtime.h>
#include <hip/hip_bf16.h>
#include <cstdint>

#define B_   16
#define C_   256
#define N_   8192
#define CN_  128
#define CL_  64
#define MID_ 128

typedef unsigned short u16;
typedef __attribute__((ext_vector_type(8))) short bf8;
typedef __attribute__((ext_vector_type(4))) float f4;

#define MFMA(a, bb, c) __builtin_amdgcn_mfma_f32_16x16x32_bf16(a, bb, c, 0, 0, 0)

// LDS-publish barrier without vmcnt drain.
#define BAR() do {                                        \
    __builtin_amdgcn_sched_barrier(0);                    \
    asm volatile("s_waitcnt lgkmcnt(0)" ::: "memory");    \
    __builtin_amdgcn_s_barrier();                         \
    __builtin_amdgcn_sched_barrier(0);                    \
  } while (0)

// 16-byte global -> LDS direct (dest = lds base + lane*16)
__device__ inline void gll16(const void* g, void* l) {
  __builtin_amdgcn_global_load_lds(
      (const __attribute__((address_space(1))) void*)g,
      (__attribute__((address_space(3))) void*)l, 16, 0, 0);
}

__device__ inline u16 f2b(float v) {
  uint32_t b = __builtin_bit_cast(uint32_t, v);
  uint32_t r = (b + 0x7FFFu + ((b >> 16) & 1u)) >> 16;
  return (u16)r;
}
__device__ inline float b2f(u16 u) {
  uint32_t b = ((uint32_t)u) << 16;
  return __builtin_bit_cast(float, b);
}
__device__ inline void st4(u16* p, u16 a, u16 b, u16 c, u16 d) {
  unsigned long long v = (unsigned long long)a | ((unsigned long long)b << 16) |
                         ((unsigned long long)c << 32) | ((unsigned long long)d << 48);
  *(unsigned long long*)p = v;
}

// ---------------------------------------------------------------------------
// K1 (merged): blocks [0, wf_base): k_att. blocks [wf_base,...): k_wfold.
// ---------------------------------------------------------------------------
__global__ __launch_bounds__(256) void k_att_wf(
    const float* __restrict__ curves, const float* __restrict__ w_att,
    float* __restrict__ attp,
    const float* __restrict__ wd, const float* __restrict__ wn,
    const float* __restrict__ wl,
    float* __restrict__ wdnT, float* __restrict__ wdlT, int wf_base) {
  const int bx = blockIdx.x;
  if (bx < wf_base) {
    const int blk = bx;
    const int b = blk >> 6, seg = (blk >> 2) & 15, cs = blk & 3;
    const int e2 = seg * 512 + threadIdx.x * 2;
    const float* cb = curves + (size_t)b * C_ * CN_ * CL_ + (size_t)cs * 64 * 8192 + e2;
    const float* w = w_att + cs * 64;
    float2 a0 = {0.f, 0.f}, a1 = a0, a2 = a0, a3 = a0;
    #pragma unroll 4
    for (int c = 0; c < 64; c += 4) {
      const float w0 = w[c + 0], w1 = w[c + 1], w2 = w[c + 2], w3 = w[c + 3];
      float2 v0 = *(const float2*)&cb[(size_t)(c + 0) * 8192];
      float2 v1 = *(const float2*)&cb[(size_t)(c + 1) * 8192];
      float2 v2 = *(const float2*)&cb[(size_t)(c + 2) * 8192];
      float2 v3 = *(const float2*)&cb[(size_t)(c + 3) * 8192];
      a0.x = fmaf(w0, v0.x, a0.x); a0.y = fmaf(w0, v0.y, a0.y);
      a1.x = fmaf(w1, v1.x, a1.x); a1.y = fmaf(w1, v1.y, a1.y);
      a2.x = fmaf(w2, v2.x, a2.x); a2.y = fmaf(w2, v2.y, a2.y);
      a3.x = fmaf(w3, v3.x, a3.x); a3.y = fmaf(w3, v3.y, a3.y);
    }
    float2 a;
    a.x = (a0.x + a1.x) + (a2.x + a3.x);
    a.y = (a0.y + a1.y) + (a2.y + a3.y);
    *(float2*)&attp[(size_t)(cs * 16 + b) * 8192 + e2] = a;
  } else {
    const int idx = (bx - wf_base) * 256 + threadIdx.x;
    const int plane = idx >> 15;
    const int r = idx & 32767;
    const int c = r & 255, m = r >> 8;
    const float* wsrc = plane ? wl : wn;
    const float* wdrow = wd + c * 256 + plane * 128;
    float a0 = 0.f, a1 = 0.f, a2 = 0.f, a3 = 0.f;
    for (int o = 0; o < 128; o += 4) {
      a0 = fmaf(wdrow[o + 0], wsrc[(o + 0) * 128 + m], a0);
      a1 = fmaf(wdrow[o + 1], wsrc[(o + 1) * 128 + m], a1);
      a2 = fmaf(wdrow[o + 2], wsrc[(o + 2) * 128 + m], a2);
      a3 = fmaf(wdrow[o + 3], wsrc[(o + 3) * 128 + m], a3);
    }
    (plane ? wdlT : wdnT)[m * 256 + c] = (a0 + a1) + (a2 + a3);
  }
}

// ---------------------------------------------------------------------------
// K2 (merged): blocks [0, sm_cnt): dual softmax. blocks [sm_cnt,...): k_wfold2.
// ---------------------------------------------------------------------------
__global__ __launch_bounds__(256) void k_sm_wf2(
    const float* __restrict__ attp, float* __restrict__ smi,
    float* __restrict__ sma,
    const float* __restrict__ wa, const float* __restrict__ wb,
    const float* __restrict__ wc,
    const float* __restrict__ wdnT, const float* __restrict__ wdlT,
    float* __restrict__ Wac, float* __restrict__ Wna,
    float* __restrict__ Wbc, float* __restrict__ Wlb, int sm_cnt) {
  const int bx = blockIdx.x;
  if (bx < sm_cnt) {
    __shared__ float T[CN_ * CL_];
    __shared__ float rmax[CN_], rrcp[CN_], cmax[CL_], crcp[CL_];
    const int b = bx;
    const int tid = threadIdx.x;
    for (int idx = tid; idx < CN_ * CL_; idx += 256) {
      T[idx] = attp[(size_t)b * 8192 + idx]
             + attp[(size_t)(16 + b) * 8192 + idx]
             + attp[(size_t)(32 + b) * 8192 + idx]
             + attp[(size_t)(48 + b) * 8192 + idx];
    }
    __syncthreads();
    if (tid < 128) {
      const int n = tid;
      float mx = -1e30f;
      for (int l = 0; l < CL_; ++l) mx = fmaxf(mx, T[n * 64 + l]);
      float s = 0.f;
      for (int l = 0; l < CL_; ++l) s += __expf(T[n * 64 + l] - mx);
      rmax[n] = mx; rrcp[n] = 1.f / s;
    } else if (tid < 192) {
      const int l = tid - 128;
      float mx = -1e30f;
      for (int n = 0; n < CN_; ++n) mx = fmaxf(mx, T[n * 64 + l]);
      float s = 0.f;
      for (int n = 0; n < CN_; ++n) s += __expf(T[n * 64 + l] - mx);
      cmax[l] = mx; crcp[l] = 1.f / s;
    }
    __syncthreads();
    for (int idx = tid; idx < CN_ * CL_; idx += 256) {
      const int n = idx >> 6, l = idx & 63;
      const float v = T[idx];
      smi[b * 8192 + idx] = __expf(v - rmax[n]) * rrcp[n];
      sma[b * 8192 + idx] = __expf(v - cmax[l]) * crcp[l];
    }
  } else {
    const int idx = (bx - sm_cnt) * 256 + threadIdx.x;
    const int quad = idx >> 16;
    const int r = idx & 65535;
    const int cc = r & 255, c = r >> 8;
    const float* L = (quad & 2) ? wb : wa;
    const float* R = (quad & 1) ? ((quad & 2) ? wdlT : wdnT) : wc;
    float a0 = 0.f, a1 = 0.f, a2 = 0.f, a3 = 0.f;
    for (int m = 0; m < 128; m += 4) {
      a0 = fmaf(L[(m + 0) * 256 + c], R[(m + 0) * 256 + cc], a0);
      a1 = fmaf(L[(m + 1) * 256 + c], R[(m + 1) * 256 + cc], a1);
      a2 = fmaf(L[(m + 2) * 256 + c], R[(m + 2) * 256 + cc], a2);
      a3 = fmaf(L[(m + 3) * 256 + c], R[(m + 3) * 256 + cc], a3);
    }
    float* O = (quad == 0) ? Wac : (quad == 1) ? Wna : (quad == 2) ? Wbc : Wlb;
    O[c * 256 + cc] = (a0 + a1) + (a2 + a3);
  }
}

// ---------------------------------------------------------------------------
// K3: curve aggregation — ALL 256 threads in both reduce phases.
// Phase 1 (cinter): 2 threads/n, 32-l halves, shfl_xor(1) combine.
// Phase 2 (cintra): 4 threads/l, 32-n quarters, shfl_xor(1,2) combine.
// Same arithmetic terms as r19; re-associated only.
// ---------------------------------------------------------------------------
__global__ __launch_bounds__(256) void k_agg(const float* __restrict__ curves,
                                             const float* __restrict__ smi,
                                             const float* __restrict__ sma,
                                             float* __restrict__ cinter,
                                             float* __restrict__ cintra) {
  __shared__ float P[CN_ * CL_];
  const int blk = blockIdx.x;
  const int b = blk >> 8, c = blk & 255;
  const int tid = threadIdx.x;
  const float* src = curves + (size_t)(b * 256 + c) * 8192;
  for (int i4 = tid; i4 < 2048; i4 += 256)
    *(float4*)&P[i4 * 4] = *(const float4*)&src[i4 * 4];
  __syncthreads();

  // ---- phase 1: cinter[b,c,n] = sum_l P[n][l]*smi[b,n,l]
  {
    const int n = tid >> 1, q = tid & 1;           // 2 threads per n
    const float* sp = smi + (size_t)(b * 128 + n) * 64 + q * 32;
    const float* pp = &P[n * 64 + q * 32];
    float4 a0 = {0.f, 0.f, 0.f, 0.f}, a1 = a0;
    #pragma unroll
    for (int l0 = 0; l0 < 32; l0 += 8) {
      float4 p0 = *(const float4*)&pp[l0];
      float4 s0 = *(const float4*)&sp[l0];
      float4 p1 = *(const float4*)&pp[l0 + 4];
      float4 s1 = *(const float4*)&sp[l0 + 4];
      a0.x = fmaf(p0.x, s0.x, a0.x); a0.y = fmaf(p0.y, s0.y, a0.y);
      a0.z = fmaf(p0.z, s0.z, a0.z); a0.w = fmaf(p0.w, s0.w, a0.w);
      a1.x = fmaf(p1.x, s1.x, a1.x); a1.y = fmaf(p1.y, s1.y, a1.y);
      a1.z = fmaf(p1.z, s1.z, a1.z); a1.w = fmaf(p1.w, s1.w, a1.w);
    }
    float s = ((a0.x + a1.x) + (a0.y + a1.y)) + ((a0.z + a1.z) + (a0.w + a1.w));
    s += __shfl_xor(s, 1);
    if (q == 0) cinter[(size_t)(b * 256 + c) * 128 + n] = s;
  }

  // ---- phase 2: cintra[b,c,l] = sum_n P[n][l]*sma[b,n,l]
  {
    const int l = tid >> 2, q = tid & 3;           // 4 threads per l
    const int n0 = q * 32;
    const float* sb = sma + (size_t)(b * 128 + n0) * 64 + l;
    float a[4] = {0.f, 0.f, 0.f, 0.f};
    #pragma unroll
    for (int k = 0; k < 32; k += 4) {
      a[0] = fmaf(P[(n0 + k + 0) * 64 + l], sb[(k + 0) * 64], a[0]);
      a[1] = fmaf(P[(n0 + k + 1) * 64 + l], sb[(k + 1) * 64], a[1]);
      a[2] = fmaf(P[(n0 + k + 2) * 64 + l], sb[(k + 2) * 64], a[2]);
      a[3] = fmaf(P[(n0 + k + 3) * 64 + l], sb[(k + 3) * 64], a[3]);
    }
    float s = (a[0] + a[1]) + (a[2] + a[3]);
    s += __shfl_xor(s, 1);
    s += __shfl_xor(s, 2);
    if (q == 0) cintra[(size_t)(b * 256 + c) * 64 + l] = s;
  }
}

// ---------------------------------------------------------------------------
// K4: fold per batch, K=256 over c from cinter/cintra (unchanged).
// ---------------------------------------------------------------------------
__global__ __launch_bounds__(256) void k_fold(
    const float* __restrict__ cinter, const float* __restrict__ cintra,
    const float* __restrict__ Wac, const float* __restrict__ Wna,
    const float* __restrict__ Wbc, const float* __restrict__ Wlb,
    u16* __restrict__ AnH, u16* __restrict__ AnL,
    u16* __restrict__ BlH, u16* __restrict__ BlL,
    u16* __restrict__ Wy) {
  __shared__ float S1[64 * 65], S2[64 * 65];
  const int blk = blockIdx.x;
  const int b = blk / 24, tile = blk - b * 24;
  const int tid = threadIdx.x;
  const int r = tid & 63, c4 = tid >> 6;
  float acc[16];
  #pragma unroll
  for (int i = 0; i < 16; ++i) acc[i] = 0.f;

  int n0 = 0, c0 = 0, type;
  if (tile < 8)       { type = 0; n0 = (tile >> 2) * 64; c0 = (tile & 3) * 64; }
  else if (tile < 12) { type = 1; c0 = (tile - 8) * 64; }
  else if (tile < 20) { type = 2; c0 = ((tile - 12) >> 1) * 64; n0 = ((tile - 12) & 1) * 64; }
  else                { type = 3; c0 = (tile - 20) * 64; }

  const float* cib = cinter + (size_t)b * 32768;
  const float* ctb = cintra + (size_t)b * 16384;

  for (int kh = 0; kh < 4; ++kh) {
    __syncthreads();
    if (type == 0) {
      for (int it = 0; it < 16; ++it) {
        const int flat = it * 256 + tid, cl = flat >> 6, j = flat & 63;
        const int c = kh * 64 + cl;
        S1[cl * 65 + j] = Wac[c * 256 + c0 + j];
        S2[cl * 65 + j] = cib[c * 128 + n0 + j];
      }
    } else if (type == 1) {
      for (int it = 0; it < 16; ++it) {
        const int flat = it * 256 + tid, cl = flat >> 6, j = flat & 63;
        const int c = kh * 64 + cl;
        S1[cl * 65 + j] = Wbc[c * 256 + c0 + j];
        S2[cl * 65 + j] = ctb[c * 64 + j];
      }
    } else if (type == 2) {
      for (int it = 0; it < 16; ++it) {
        const int flat = it * 256 + tid, cl = flat >> 6, j = flat & 63;
        const int c = kh * 64 + cl;
        S1[cl * 65 + j] = cib[c * 128 + n0 + j];
        S2[cl * 65 + j] = Wna[c * 256 + c0 + j];
      }
    } else {
      for (int it = 0; it < 16; ++it) {
        const int flat = it * 256 + tid, cl = flat >> 6, j = flat & 63;
        const int c = kh * 64 + cl;
        S1[cl * 65 + j] = ctb[c * 64 + j];
        S2[cl * 65 + j] = Wlb[c * 256 + c0 + j];
      }
    }
    __syncthreads();
    for (int k = 0; k < 64; ++k) {
      const float va = S1[k * 65 + r];
      #pragma unroll
      for (int cc = 0; cc < 16; ++cc)
        acc[cc] = fmaf(va, S2[k * 65 + c4 * 16 + cc], acc[cc]);
    }
  }

  if (type == 0) {
    #pragma unroll
    for (int cc = 0; cc < 16; ++cc) {
      const float v = acc[cc];
      const u16 h = f2b(v);
      const size_t o = (size_t)b * 32768 + (n0 + c4 * 16 + cc) * 256 + c0 + r;
      AnH[o] = h; AnL[o] = f2b(v - b2f(h));
    }
  } else if (type == 1) {
    #pragma unroll
    for (int cc = 0; cc < 16; ++cc) {
      const float v = acc[cc];
      const u16 h = f2b(v);
      const size_t o = (size_t)b * 16384 + (c4 * 16 + cc) * 256 + c0 + r;
      BlH[o] = h; BlL[o] = f2b(v - b2f(h));
    }
  } else if (type == 2) {
    #pragma unroll
    for (int cc = 0; cc < 16; ++cc)
      Wy[(size_t)b * 49152 + (c0 + c4 * 16 + cc) * 192 + n0 + r] = f2b(acc[cc]);
  } else {
    #pragma unroll
    for (int cc = 0; cc < 16; ++cc)
      Wy[(size_t)b * 49152 + (c0 + c4 * 16 + cc) * 192 + 128 + r] = f2b(acc[cc]);
  }
}

// ---------------------------------------------------------------------------
// K5: k_big — r18 verbatim (gll A-staging, X bf16, p-tile 128, 66 KB LDS).
// ---------------------------------------------------------------------------
__global__ __launch_bounds__(256, 2) void k_big(
    const float* __restrict__ x,
    const u16* __restrict__ AnH, const u16* __restrict__ AnL,
    const u16* __restrict__ BlH, const u16* __restrict__ BlL,
    const u16* __restrict__ Wy,
    const float* __restrict__ bng, const float* __restrict__ bnb,
    const float* __restrict__ bnm, const float* __restrict__ bnv,
    float* __restrict__ out) {
  __shared__ __align__(16) u16 LDS[33792];
  float* scL = (float*)(LDS + 32768);
  float* biL = (float*)(LDS + 33280);

  const int tid  = threadIdx.x;
  const int lane = tid & 63;
  const int wid  = tid >> 6;
  const int l15  = lane & 15;
  const int lg   = lane >> 4;
  const int p    = wid * 16 + l15;
  const int blk  = blockIdx.x;
  const int wg   = ((blk & 7) << 7) | (blk >> 3);
  const int b    = wg >> 6;
  const int p0g  = (wg & 63) << 7;
  const f4 zero4 = {0.f, 0.f, 0.f, 0.f};

  const u16* AnHb = AnH + ((size_t)b << 15);
  const u16* AnLb = AnL + ((size_t)b << 15);
  const u16* BlHb = BlH + ((size_t)b << 14);
  const u16* BlLb = BlL + ((size_t)b << 14);
  const u16* Wyb  = Wy  + (size_t)b * 49152;

  {
    const float scv = bng[tid] * rsqrtf(bnv[tid] + 1e-5f);
    scL[tid] = scv;
    biL[tid] = bnb[tid] - bnm[tid] * scv;
  }

  const int xp  = tid & 127;
  const int xkc = tid >> 7;
  const float* xb = x + (size_t)b * C_ * N_ + p0g;
  const int xswp = (xp >> 1) & 3;
  const int xo0 = 24576 + xp * 32 + (((2 * xkc + 0) ^ xswp) * 8);
  const int xo1 = 24576 + xp * 32 + (((2 * xkc + 1) ^ xswp) * 8);

  const u16* aSrc[6];
  #pragma unroll
  for (int j = 0; j < 6; ++j) {
    const int cid = j * 256 + tid;
    const int plane = (cid >= 768) ? 1 : 0;
    const int rr = cid - plane * 768;
    const int row = rr >> 2, kc = rr & 3;
    const u16* base;
    if (row < 128) base = (plane ? AnLb : AnHb) + row * 256;
    else           base = (plane ? BlLb : BlHb) + (row - 128) * 256;
    aSrc[j] = base + 8 * (kc ^ ((row >> 1) & 3));
  }
  int aDstW[6];
  #pragma unroll
  for (int j = 0; j < 6; ++j) aDstW[j] = 8 * (j * 256 + wid * 64);

  const u16* wSrc[4];
  int wLds[4];
  #pragma unroll
  for (int j = 0; j < 4; ++j) {
    const int cid = j * 256 + tid;
    const int row = cid >> 2, kc = cid & 3;
    wSrc[j] = Wyb + row * 192 + 8 * (kc ^ ((row >> 1) & 3));
    wLds[j] = 24576 + row * 32 + kc * 8;
  }

  // ================= SCORE PHASE =================
  f4 accS[8][2], accA[4][2];
  #pragma unroll
  for (int t = 0; t < 8; ++t) { accS[t][0] = zero4; accS[t][1] = zero4; }
  #pragma unroll
  for (int t = 0; t < 4; ++t) { accA[t][0] = zero4; accA[t][1] = zero4; }

  float xRaw[2][16];

  #pragma unroll
  for (int j = 0; j < 6; ++j) gll16(aSrc[j], LDS + aDstW[j]);
  #pragma unroll
  for (int jj = 0; jj < 16; ++jj)
    xRaw[0][jj] = xb[(size_t)(xkc * 16 + jj) * N_ + xp];
  {
    bf8 h0, h1;
    #pragma unroll
    for (int jj = 0; jj < 8; ++jj) {
      h0[jj] = (short)f2b(xRaw[0][jj]);
      h1[jj] = (short)f2b(xRaw[0][8 + jj]);
    }
    *(bf8*)(LDS + xo0) = h0;
    *(bf8*)(LDS + xo1) = h1;
  }
  #pragma unroll
  for (int jj = 0; jj < 16; ++jj)
    xRaw[1][jj] = xb[(size_t)(32 + xkc * 16 + jj) * N_ + xp];
  __syncthreads();

  const int rswp = (p >> 1) & 3;
  #pragma unroll
  for (int q = 0; q < 8; ++q) {
    const int cbuf = (q & 1) * 12288;
    if (q < 7) {
      const int nbuf = ((q + 1) & 1) * 12288;
      #pragma unroll
      for (int j = 0; j < 6; ++j)
        gll16(aSrc[j] + (q + 1) * 32, LDS + nbuf + aDstW[j]);
    }
    if (q < 6) {
      #pragma unroll
      for (int jj = 0; jj < 16; ++jj)
        xRaw[q & 1][jj] = xb[(size_t)((q + 2) * 32 + xkc * 16 + jj) * N_ + xp];
    }
    const bf8 xh0 = *(const bf8*)(LDS + 24576 + p * 32 + ((lg ^ rswp) * 8));
    const bf8 xh1 = *(const bf8*)(LDS + 24576 + (p + 64) * 32 + ((lg ^ rswp) * 8));
    #pragma unroll
    for (int t = 0; t < 8; ++t) {
      const int row = t * 16 + l15;
      const int sw = 8 * (lg ^ ((row >> 1) & 3));
      const bf8 ah = *(const bf8*)(LDS + cbuf + row * 32 + sw);
      const bf8 al = *(const bf8*)(LDS + cbuf + 6144 + row * 32 + sw);
      accS[t][0] = MFMA(ah, xh0, accS[t][0]);
      accS[t][0] = MFMA(al, xh0, accS[t][0]);
      accS[t][1] = MFMA(ah, xh1, accS[t][1]);
      accS[t][1] = MFMA(al, xh1, accS[t][1]);
    }
    #pragma unroll
    for (int t = 0; t < 4; ++t) {
      const int row = 128 + t * 16 + l15;
      const int sw = 8 * (lg ^ ((row >> 1) & 3));
      const bf8 ah = *(const bf8*)(LDS + cbuf + row * 32 + sw);
      const bf8 al = *(const bf8*)(LDS + cbuf + 6144 + row * 32 + sw);
      accA[t][0] = MFMA(ah, xh0, accA[t][0]);
      accA[t][0] = MFMA(al, xh0, accA[t][0]);
      accA[t][1] = MFMA(ah, xh1, accA[t][1]);
      accA[t][1] = MFMA(al, xh1, accA[t][1]);
    }
    bf8 nh0, nh1;
    if (q < 7) {
      #pragma unroll
      for (int jj = 0; jj < 8; ++jj) {
        nh0[jj] = (short)f2b(xRaw[(q + 1) & 1][jj]);
        nh1[jj] = (short)f2b(xRaw[(q + 1) & 1][8 + jj]);
      }
    }
    __syncthreads();
    if (q < 7) {
      *(bf8*)(LDS + xo0) = nh0;
      *(bf8*)(LDS + xo1) = nh1;
      BAR();
    }
  }

  // ================= SOFTMAX + E + Wy(0) =================
  bf8 wReg[4];
  #pragma unroll
  for (int j = 0; j < 4; ++j) wReg[j] = *(const bf8*)(wSrc[j]);

  u16* E = LDS;
  #pragma unroll
  for (int s = 0; s < 2; ++s) {
    const int ps = p + s * 64;
    float mx = -3.0e38f;
    #pragma unroll
    for (int t = 0; t < 8; ++t)
      #pragma unroll
      for (int r = 0; r < 4; ++r) mx = fmaxf(mx, accS[t][s][r]);
    mx = fmaxf(mx, __shfl_xor(mx, 16));
    mx = fmaxf(mx, __shfl_xor(mx, 32));
    float sum = 0.f;
    #pragma unroll
    for (int t = 0; t < 8; ++t)
      #pragma unroll
      for (int r = 0; r < 4; ++r) {
        const float e = __expf(accS[t][s][r] - mx);
        accS[t][s][r] = e; sum += e;
      }
    sum += __shfl_xor(sum, 16);
    sum += __shfl_xor(sum, 32);
    const float rcp = 1.f / sum;
    #pragma unroll
    for (int t = 0; t < 8; ++t) {
      const int j0 = t * 16 + lg * 4;
      const int chunk = j0 >> 3;
      const int csw = (chunk & ~7) | ((chunk & 7) ^ (ps & 7));
      st4(E + ps * 192 + csw * 8 + (j0 & 7),
          f2b(accS[t][s][0] * rcp), f2b(accS[t][s][1] * rcp),
          f2b(accS[t][s][2] * rcp), f2b(accS[t][s][3] * rcp));
    }
    float mx2 = -3.0e38f;
    #pragma unroll
    for (int t = 0; t < 4; ++t)
      #pragma unroll
      for (int r = 0; r < 4; ++r) mx2 = fmaxf(mx2, accA[t][s][r]);
    mx2 = fmaxf(mx2, __shfl_xor(mx2, 16));
    mx2 = fmaxf(mx2, __shfl_xor(mx2, 32));
    float sum2 = 0.f;
    #pragma unroll
    for (int t = 0; t < 4; ++t)
      #pragma unroll
      for (int r = 0; r < 4; ++r) {
        const float e = __expf(accA[t][s][r] - mx2);
        accA[t][s][r] = e; sum2 += e;
      }
    sum2 += __shfl_xor(sum2, 16);
    sum2 += __shfl_xor(sum2, 32);
    const float rcp2 = 1.f / sum2;
    #pragma unroll
    for (int t = 0; t < 4; ++t) {
      const int j0 = 128 + t * 16 + lg * 4;
      const int chunk = j0 >> 3;
      const int csw = (chunk & ~7) | ((chunk & 7) ^ (ps & 7));
      st4(E + ps * 192 + csw * 8 + (j0 & 7),
          f2b(accA[t][s][0] * rcp2), f2b(accA[t][s][1] * rcp2),
          f2b(accA[t][s][2] * rcp2), f2b(accA[t][s][3] * rcp2));
    }
  }
  #pragma unroll
  for (int j = 0; j < 4; ++j) *(bf8*)(LDS + wLds[j]) = wReg[j];
  BAR();

  // ================= OUT PHASE: y = Wy @ E (K=192, 6 steps) ===============
  f4 acc8[16][2];
  #pragma unroll
  for (int t = 0; t < 16; ++t) { acc8[t][0] = zero4; acc8[t][1] = zero4; }

  #pragma unroll
  for (int q = 0; q < 6; ++q) {
    if (q < 5) {
      #pragma unroll
      for (int j = 0; j < 4; ++j) wReg[j] = *(const bf8*)(wSrc[j] + (q + 1) * 32);
    }
    const int jchunk = q * 4 + lg;
    const int cs0 = (jchunk & ~7) | ((jchunk & 7) ^ (p & 7));
    const bf8 ef0 = *(const bf8*)(E + p * 192 + cs0 * 8);
    const bf8 ef1 = *(const bf8*)(E + (p + 64) * 192 + cs0 * 8);
    #pragma unroll
    for (int t = 0; t < 16; ++t) {
      const int row = t * 16 + l15;
      const int sw = 8 * (lg ^ ((row >> 1) & 3));
      const bf8 wf = *(const bf8*)(LDS + 24576 + row * 32 + sw);
      acc8[t][0] = MFMA(wf, ef0, acc8[t][0]);
      acc8[t][1] = MFMA(wf, ef1, acc8[t][1]);
    }
    BAR();
    if (q < 5) {
      #pragma unroll
      for (int j = 0; j < 4; ++j) *(bf8*)(LDS + wLds[j]) = wReg[j];
      BAR();
    }
  }

  // ================= EPILOGUE =================
  const size_t pcol = (size_t)p0g + p;
  #pragma unroll
  for (int t = 0; t < 16; ++t) {
    #pragma unroll
    for (int r = 0; r < 4; ++r) {
      const int c = t * 16 + lg * 4 + r;
      const float sc = scL[c], bi = biL[c];
      const size_t o0 = (((size_t)b * 256 + c) << 13) + pcol;
      const float z0 = x[o0] + acc8[t][0][r] * sc + bi;
      out[o0] = z0 > 0.f ? z0 : 0.2f * z0;
      const size_t o1 = o0 + 64;
      const float z1 = x[o1] + acc8[t][1][r] * sc + bi;
      out[o1] = z1 > 0.f ? z1 : 0.2f * z1;
    }
  }
}

// ---------------------------------------------------------------------------
extern "C" void kernel_launch(void* const* d_in, const int* in_sizes, int n_in,
                              void* d_out, int out_size, void* d_ws, size_t ws_size,
                              hipStream_t stream) {
  const float* x      = (const float*)d_in[0];
  const float* curves = (const float*)d_in[1];
  const float* w_att  = (const float*)d_in[2];
  const float* wa     = (const float*)d_in[3];
  const float* wb     = (const float*)d_in[4];
  const float* wc     = (const float*)d_in[5];
  const float* wn     = (const float*)d_in[6];
  const float* wl     = (const float*)d_in[7];
  const float* wd     = (const float*)d_in[8];
  const float* bng    = (const float*)d_in[9];
  const float* bnb    = (const float*)d_in[10];
  const float* bnm    = (const float*)d_in[11];
  const float* bnv    = (const float*)d_in[12];
  float* out = (float*)d_out;
  float* ws  = (float*)d_ws;
  u16* wsb = (u16*)d_ws;

  if (ws_size >= (size_t)2359296 * 4) {
    // ---- race-free layout (9 MiB), merged launches (5 kernels) ----
    float* wdnT   = ws + 0;
    float* wdlT   = ws + 32768;
    float* smi    = ws + 131072;
    float* sma    = ws + 262144;
    float* attp   = ws + 393216;
    float* Wac    = ws + 917504;
    float* Wna    = ws + 983040;
    float* Wbc    = ws + 1048576;
    float* Wlb    = ws + 1114112;
    float* cinter = ws + 1179648;
    float* cintra = ws + 1703936;
    u16* AnH = wsb;
    u16* AnL = wsb + 524288;
    u16* BlH = wsb + 1048576;
    u16* BlL = wsb + 1310720;
    u16* Wyp = wsb + 3932160;

    k_att_wf<<<dim3(1280),   dim3(256), 0, stream>>>(curves, w_att, attp,
                                                     wd, wn, wl, wdnT, wdlT, 1024);
    k_sm_wf2<<<dim3(1040),   dim3(256), 0, stream>>>(attp, smi, sma, wa, wb, wc,
                                                     wdnT, wdlT, Wac, Wna, Wbc, Wlb, 16);
    k_agg   <<<dim3(B_ * C_), dim3(256), 0, stream>>>(curves, smi, sma, cinter, cintra);
    k_fold  <<<dim3(B_ * 24), dim3(256), 0, stream>>>(cinter, cintra,
                                                      Wac, Wna, Wbc, Wlb,
                                                      AnH, AnL, BlH, BlL, Wyp);
    k_big   <<<dim3(1024),   dim3(256), 0, stream>>>(x, AnH, AnL, BlH, BlL, Wyp,
                                                     bng, bnb, bnm, bnv, out);
  } else {
    // ---- fallback: r18 layout & sequence (7.5 MiB proven) ----
    float* smi    = ws + 131072;
    float* sma    = ws + 262144;
    float* cinter = ws + 393216;
    float* cintra = ws + 917504;
    float* attp   = ws + 1179648;
    float* Wac    = ws + 1179648;
    float* Wna    = ws + 1245184;
    float* Wbc    = ws + 1310720;
    float* Wlb    = ws + 1376256;
    float* wdnT   = ws + 1441792;
    float* wdlT   = ws + 1474560;
    u16* AnH = wsb;
    u16* AnL = wsb + 524288;
    u16* BlH = wsb + 1048576;
    u16* BlL = wsb + 1310720;
    u16* Wyp = wsb + 1572864;

    k_att_wf<<<dim3(1024),   dim3(256), 0, stream>>>(curves, w_att, attp,
                                                     wd, wn, wl, wdnT, wdlT, 1024);
    k_sm_wf2<<<dim3(16),     dim3(256), 0, stream>>>(attp, smi, sma, wa, wb, wc,
                                                     wdnT, wdlT, Wac, Wna, Wbc, Wlb, 16);
    k_att_wf<<<dim3(256),    dim3(256), 0, stream>>>(curves, w_att, attp,
                                                     wd, wn, wl, wdnT, wdlT, 0);
    k_sm_wf2<<<dim3(1024),   dim3(256), 0, stream>>>(attp, smi, sma, wa, wb, wc,
                                                     wdnT, wdlT, Wac, Wna, Wbc, Wlb, 0);
    k_agg   <<<dim3(B_ * C_), dim3(256), 0, stream>>>(curves, smi, sma, cinter, cintra);
    k_fold  <<<dim3(B_ * 24), dim3(256), 0, stream>>>(cinter, cintra,
                                                      Wac, Wna, Wbc, Wlb,
                                                      AnH, AnL, BlH, BlL, Wyp);
    k_big   <<<dim3(1024),   dim3(256), 0, stream>>>(x, AnH, AnL, BlH, BlL, Wyp,
                                                     bng, bnb, bnm, bnv, out);
  }
}